// Round 1
// baseline (79.318 us; speedup 1.0000x reference)
//
#include <hip/hip_runtime.h>
#include <hip/hip_bf16.h>

#define B_    128
#define CIN_  64
#define H_    32
#define W_    32
#define COUT_ 64
#define HP    34
#define WP    34
#define KTOT  576   // CIN * 3 * 3

typedef __attribute__((ext_vector_type(8))) short  short8;
typedef __attribute__((ext_vector_type(4))) float  f32x4;

__device__ __forceinline__ unsigned short f2bf(float f) {
  union { float f; unsigned int u; } v; v.f = f;
  unsigned int r = (v.u + 0x7FFFu + ((v.u >> 16) & 1u)) >> 16;  // RNE
  return (unsigned short)r;
}

// ---------------------------------------------------------------------------
// Pre-pass: xTp[c][hp][wp][b] (bf16), hp/wp in [0,34) with zero border rows.
// xTp[c][hp][wp][b] = x[b][c][hp-1][wp-1]  (0 if out of range)
// ---------------------------------------------------------------------------
__global__ __launch_bounds__(256) void xT_kernel(const float* __restrict__ x,
                                                 unsigned short* __restrict__ xTp) {
  const int c  = blockIdx.x;   // 0..63
  const int hp = blockIdx.y;   // 0..33
  const int t  = threadIdx.x;  // 0..255
  unsigned short* dst = xTp + ((size_t)(c * HP + hp)) * (WP * B_);

  if (hp == 0 || hp == HP - 1) {
    const uint4 z = make_uint4(0u, 0u, 0u, 0u);
    for (int i = t; i < (WP * B_ * 2) / 16; i += 256) ((uint4*)dst)[i] = z;
    return;
  }

  __shared__ unsigned short tile[B_][W_ + 1];
  const int b = t >> 1, half = t & 1;
  const float4* s4 = (const float4*)(x + ((size_t)b * CIN_ + c) * (H_ * W_) +
                                     (hp - 1) * W_ + half * 16);
#pragma unroll
  for (int i = 0; i < 4; ++i) {
    float4 v = s4[i];
    const int w0 = half * 16 + i * 4;
    tile[b][w0 + 0] = f2bf(v.x);
    tile[b][w0 + 1] = f2bf(v.y);
    tile[b][w0 + 2] = f2bf(v.z);
    tile[b][w0 + 3] = f2bf(v.w);
  }
  __syncthreads();

  for (int wp = t >> 4; wp < WP; wp += 16) {
    const int b0 = (t & 15) * 8;
    unsigned short vals[8];
    if (wp == 0 || wp == WP - 1) {
#pragma unroll
      for (int j = 0; j < 8; ++j) vals[j] = 0;
    } else {
#pragma unroll
      for (int j = 0; j < 8; ++j) vals[j] = tile[b0 + j][wp - 1];
    }
    uint4 pk;
    pk.x = (unsigned)vals[0] | ((unsigned)vals[1] << 16);
    pk.y = (unsigned)vals[2] | ((unsigned)vals[3] << 16);
    pk.z = (unsigned)vals[4] | ((unsigned)vals[5] << 16);
    pk.w = (unsigned)vals[6] | ((unsigned)vals[7] << 16);
    ((uint4*)(dst + wp * B_))[t & 15] = pk;
  }
}

// ---------------------------------------------------------------------------
// Main: one block per (h,w). GEMM M=128(b) x N=64(d) x K=576 via
// mfma_f32_16x16x32_bf16. 4 waves, wave wv owns b-rows [wv*32, wv*32+32).
// ---------------------------------------------------------------------------
__global__ __launch_bounds__(256) void lc_main(const float* __restrict__ Wt,
                                               const float* __restrict__ bias,
                                               const unsigned short* __restrict__ xTp,
                                               float* __restrict__ out) {
  __shared__ unsigned short Wlds[COUT_][40];  // pitch 80 B (16-B aligned rows)
  __shared__ unsigned int   alds[KTOT];       // per-k base address into xTp
  __shared__ float          blds[COUT_];

  const int bid = (int)blockIdx.x;
  const int swz = (bid & 7) * 128 + (bid >> 3);  // XCD-contiguous (h,w) ranges
  const int h = swz >> 5, w = swz & 31;
  const int t    = threadIdx.x;
  const int lane = t & 63;
  const int wv   = t >> 6;
  const int l15  = lane & 15;
  const int lg   = lane >> 4;
  const int hw   = h * W_ + w;

  if (t < COUT_) blds[t] = bias[t * (H_ * W_) + hw];
  for (int i = t; i < KTOT; i += 256) {
    const int c = i / 9, r = i - c * 9, p = r / 3, q = r - p * 3;
    alds[i] = ((unsigned)((c * HP + (h + p)) * WP + (w + q))) * B_;
  }

  const float* Whw = Wt + (size_t)hw * (COUT_ * KTOT);
  const int b_lo = wv * 32 + l15;

  f32x4 acc[2][4];
#pragma unroll
  for (int bt = 0; bt < 2; ++bt)
#pragma unroll
    for (int dt = 0; dt < 4; ++dt) acc[bt][dt] = (f32x4){0.f, 0.f, 0.f, 0.f};

  const int ds = t >> 2;        // weight row d this thread stages
  const int js = (t & 3) * 8;   // 8-float slice within 32-k chunk

  for (int step = 0; step < 18; ++step) {
    const int kc = step * 32;
    __syncthreads();
    {  // stage W[64][kc..kc+32) -> bf16 LDS
      const float* src = Whw + ds * KTOT + kc + js;
      const float4 a = ((const float4*)src)[0];
      const float4 b = ((const float4*)src)[1];
      uint4 pk;
      pk.x = (unsigned)f2bf(a.x) | ((unsigned)f2bf(a.y) << 16);
      pk.y = (unsigned)f2bf(a.z) | ((unsigned)f2bf(a.w) << 16);
      pk.z = (unsigned)f2bf(b.x) | ((unsigned)f2bf(b.y) << 16);
      pk.w = (unsigned)f2bf(b.z) | ((unsigned)f2bf(b.w) << 16);
      *(uint4*)&Wlds[ds][js] = pk;
    }
    __syncthreads();

    // A fragments (x patch), per-lane gather from xTp (b-contiguous)
    short8 a0, a1;
#pragma unroll
    for (int v = 0; v < 8; ++v) {
      const unsigned base = alds[kc + lg * 8 + v];
      a0[v] = (short)xTp[base + b_lo];
      a1[v] = (short)xTp[base + b_lo + 16];
    }
    // B fragments (weight) from LDS
    short8 bfr[4];
#pragma unroll
    for (int dt = 0; dt < 4; ++dt)
      bfr[dt] = *(const short8*)&Wlds[dt * 16 + l15][lg * 8];

#pragma unroll
    for (int dt = 0; dt < 4; ++dt) {
      acc[0][dt] = __builtin_amdgcn_mfma_f32_16x16x32_bf16(a0, bfr[dt], acc[0][dt], 0, 0, 0);
      acc[1][dt] = __builtin_amdgcn_mfma_f32_16x16x32_bf16(a1, bfr[dt], acc[1][dt], 0, 0, 0);
    }
  }

  // epilogue: D col = lane&15 (d), row = (lane>>4)*4 + i (b)  [verified mapping]
#pragma unroll
  for (int dt = 0; dt < 4; ++dt) {
    const int d  = dt * 16 + l15;
    const float bv = blds[d];
#pragma unroll
    for (int bt = 0; bt < 2; ++bt) {
#pragma unroll
      for (int i = 0; i < 4; ++i) {
        const int b = wv * 32 + bt * 16 + lg * 4 + i;
        out[(size_t)b * (COUT_ * H_ * W_) + (size_t)d * (H_ * W_) + hw] =
            acc[bt][dt][i] + bv;
      }
    }
  }
}

extern "C" void kernel_launch(void* const* d_in, const int* in_sizes, int n_in,
                              void* d_out, int out_size, void* d_ws, size_t ws_size,
                              hipStream_t stream) {
  const float* x    = (const float*)d_in[0];
  const float* wt   = (const float*)d_in[1];
  const float* bias = (const float*)d_in[2];
  float* out        = (float*)d_out;
  unsigned short* xTp = (unsigned short*)d_ws;  // 64*34*34*128*2 B = 18.9 MB

  xT_kernel<<<dim3(CIN_, HP), 256, 0, stream>>>(x, xTp);
  lc_main<<<1024, 256, 0, stream>>>(wt, bias, xTp, out);
}